// Round 18
// baseline (665.036 us; speedup 1.0000x reference)
//
#include <hip/hip_runtime.h>
#include <stdint.h>

// GRU decoder: 65536 rows, H=256, T=12, D_OUT=64.
// R18 = R16 (register-state, swapped-operand MFMA, 8 waves x 32 rows,
// 256 blocks = 1/CU, ring-3 lane-linear panel stream, conflict-free,
// builtin permlane + rcpf) + BIAS FOLDED INTO PANELS as a 17th K-slice:
// W[row][256]=bias[row]; B gets const frag hb={1,0..}(kg=0)/{0..}(kg=1).
// Replaces 8 bias ds_reads/wave/phase (20% of the binding LDS pipe) with
// 2 reads + 2 MFMAs on slack pipes; acc C-init becomes zeros. W2 panels
// have zero bias -> slice skipped. Panel = 64x272 f16 = 34KB, padded to
// 40 x 1KB chunks for uniform 5 loads/wave (vmcnt(5)); ring-3 = 120KB.

#define TSTEPS 12
#define AS3 __attribute__((address_space(3)))

typedef _Float16 f16x8 __attribute__((ext_vector_type(8)));
typedef _Float16 f16x2 __attribute__((ext_vector_type(2)));
typedef float    f32x16 __attribute__((ext_vector_type(16)));
typedef float    f32x4  __attribute__((ext_vector_type(4)));
typedef uint32_t u32x4  __attribute__((ext_vector_type(4)));
typedef uint32_t u32x2  __attribute__((ext_vector_type(2)));

typedef AS3 uint8_t       u8l;
typedef const AS3 uint8_t cu8l;

// ws: f16 matrix [1088][272] row-major. Rows: 0-511 folded gates (r,z),
// 512-767 W1, 768-1023 W2, 1024-1087 Wp. Cols: 0-255 weights, 256 bias
// (0 for W2 rows), 257-271 zero pad. Panels p=0..16 = rows [64p,64p+64):
// 0-3 gate-r, 4-7 gate-z, 8-11 W1, 12-15 W2, 16 Wp.
#define NROWS_W   1088
#define KCOLS     272
#define ROWB      (KCOLS*2)           // 544 B/row
#define PANB      (64*ROWB)           // 34816 B/panel
#define WS_TOTAL_F16 (NROWS_W*KCOLS) // 295936
#define WS_BYTES  (WS_TOTAL_F16*2)   // 591872

__global__ void prep_weights(const float* __restrict__ gw,
                             const float* __restrict__ ow,
                             const float* __restrict__ pw,
                             const float* __restrict__ gb,
                             const float* __restrict__ ob,
                             const float* __restrict__ pb,
                             _Float16* __restrict__ ws)
{
    int idx = blockIdx.x*256 + threadIdx.x;
    if (idx >= WS_TOTAL_F16) return;
    int row = idx / KCOLS, col = idx - row*KCOLS;
    float v = 0.0f;
    if (row < 512) {                       // folded gates
        if (col < 256)      v = gw[row*512 + col] + gw[row*512 + 256 + col];
        else if (col == 256) v = gb[row];
    } else if (row < 768) {                // W1
        int r = row - 512;
        if (col < 256)      v = ow[r*512 + col];
        else if (col == 256) v = ob[r];
    } else if (row < 1024) {               // W2 (bias col stays 0)
        int r = row - 768;
        if (col < 256)      v = ow[r*512 + 256 + col];
    } else {                               // Wp
        int r = row - 1024;
        if (col < 256)      v = pw[r*256 + col];
        else if (col == 256) v = pb[r];
    }
    ws[idx] = (_Float16)v;
}

__device__ __forceinline__ float sigm(float x) {
    return __builtin_amdgcn_rcpf(1.0f + __expf(-x));
}
__device__ __forceinline__ float tanh_(float x) {
    return 1.0f - 2.0f*__builtin_amdgcn_rcpf(1.0f + __expf(2.0f*x));
}

// stage one panel (8 waves x 5 gll16, 40 chunks; chunks 34-39 are dead pad).
// chunk c holds (ks=c>>1, tile=c&1); lane l supplies
// W[64p + tile*32 + (l&31)][ks*16 + (l>>5)*8 ..+7].
// laneC = (l&31)*ROWB + (l>>5)*16.
__device__ __forceinline__ void stage(const uint8_t* __restrict__ Wp,
                                      u8l* slot, int w, int laneC)
{
    #pragma unroll
    for (int i = 0; i < 5; ++i) {
        int c    = w*5 + i;                   // chunk 0..39 (wave-uniform)
        int ks   = c >> 1, tile = c & 1;
        int s    = (c < 34) ? (laneC + tile*(32*ROWB) + ks*32) : laneC;
        __builtin_amdgcn_global_load_lds(
            (const __attribute__((address_space(1))) uint32_t*)(Wp + s),
            (AS3 uint32_t*)(slot + c*1024), 16, 0, 0);
    }
}

// C-layout e-pattern (8 outcols) -> B-frag f16x8 via permlane32_swap builtin
// (compiler inserts the VALU->permlane hazard waits; raw asm did not - R14/15).
__device__ __forceinline__ f16x8 pk8(uint32_t w01, uint32_t w23,
                                     uint32_t w45, uint32_t w67) {
    u32x2 p0 = __builtin_amdgcn_permlane32_swap(w01, w45, false, false);
    u32x2 p1 = __builtin_amdgcn_permlane32_swap(w23, w67, false, false);
    u32x4 u = { p0[0], p1[0], p0[1], p1[1] };
    return __builtin_bit_cast(f16x8, u);
}
__device__ __forceinline__ f16x8 pkS(const f32x16& a, int off) {
    f16x2 a01 = {(_Float16)sigm(a[off+0]), (_Float16)sigm(a[off+1])};
    f16x2 a23 = {(_Float16)sigm(a[off+2]), (_Float16)sigm(a[off+3])};
    f16x2 a45 = {(_Float16)sigm(a[off+4]), (_Float16)sigm(a[off+5])};
    f16x2 a67 = {(_Float16)sigm(a[off+6]), (_Float16)sigm(a[off+7])};
    return pk8(__builtin_bit_cast(uint32_t, a01), __builtin_bit_cast(uint32_t, a23),
               __builtin_bit_cast(uint32_t, a45), __builtin_bit_cast(uint32_t, a67));
}
__device__ __forceinline__ f16x8 pkT(const f32x16& a, int off) {
    f16x2 a01 = {(_Float16)tanh_(a[off+0]), (_Float16)tanh_(a[off+1])};
    f16x2 a23 = {(_Float16)tanh_(a[off+2]), (_Float16)tanh_(a[off+3])};
    f16x2 a45 = {(_Float16)tanh_(a[off+4]), (_Float16)tanh_(a[off+5])};
    f16x2 a67 = {(_Float16)tanh_(a[off+6]), (_Float16)tanh_(a[off+7])};
    return pk8(__builtin_bit_cast(uint32_t, a01), __builtin_bit_cast(uint32_t, a23),
               __builtin_bit_cast(uint32_t, a45), __builtin_bit_cast(uint32_t, a67));
}

// panel GEMM over 16 weight slices (no bias slice): for W2 (rh operand)
__device__ __forceinline__ void gemm16(cu8l* panL, const f16x8* B,
                                       f32x16& a0, f32x16& a1) {
    #pragma unroll
    for (int ks = 0; ks < 16; ++ks) {
        f16x8 w0 = *(const AS3 f16x8*)(panL + ks*2048);
        f16x8 w1 = *(const AS3 f16x8*)(panL + ks*2048 + 1024);
        a0 = __builtin_amdgcn_mfma_f32_32x32x16_f16(w0, B[ks], a0, 0, 0, 0);
        a1 = __builtin_amdgcn_mfma_f32_32x32x16_f16(w1, B[ks], a1, 0, 0, 0);
    }
}
// panel GEMM + bias slice (chunks 32,33 x hb)
__device__ __forceinline__ void gemm17(cu8l* panL, const f16x8* B, f16x8 hb,
                                       f32x16& a0, f32x16& a1) {
    gemm16(panL, B, a0, a1);
    f16x8 w0 = *(const AS3 f16x8*)(panL + 32*1024);
    f16x8 w1 = *(const AS3 f16x8*)(panL + 33*1024);
    a0 = __builtin_amdgcn_mfma_f32_32x32x16_f16(w0, hb, a0, 0, 0, 0);
    a1 = __builtin_amdgcn_mfma_f32_32x32x16_f16(w1, hb, a1, 0, 0, 0);
}

// phase: wait my panel (vmcnt(5): newer stage keeps 5 in flight) -> barrier
// -> stage 2-ahead -> compute
#define PHASE(SP, ...) do {                                                 \
    asm volatile("s_waitcnt vmcnt(5)" ::: "memory");                        \
    asm volatile("s_waitcnt lgkmcnt(0)" ::: "memory");                      \
    __builtin_amdgcn_s_barrier();                                           \
    asm volatile("" ::: "memory");                                          \
    stage(W + (size_t)(SP)*PANB, WbL + sS*40960, w, laneC);                 \
    { cu8l* panL = WbL + sC*40960 + LB; __VA_ARGS__; }                      \
    sC = (sC == 2) ? 0 : sC + 1;                                            \
    sS = (sS == 2) ? 0 : sS + 1;                                            \
} while (0)

__global__ __launch_bounds__(512, 1)
void gru_dec(const float* __restrict__ h_in, const _Float16* __restrict__ Wf,
             float* __restrict__ out)
{
    __shared__ __align__(16) uint8_t lds_[122880];
    u8l* WbL = (u8l*)lds_;                // 3 x 40KB panel ring
    const uint8_t* W = (const uint8_t*)Wf;

    const int tid  = threadIdx.x;
    const int lane = tid & 63;
    const int w    = tid >> 6;            // wave 0..7, owns 32 rows
    const int bl31 = lane & 31;
    const int kg   = lane >> 5;
    const size_t rowg = (size_t)blockIdx.x*256 + w*32 + bl31;

    const int laneC = bl31*ROWB + kg*16;  // per-lane stage source constant
    const int LB    = lane*16;            // per-lane ds-read base

    // bias B-frag: k'=0 column is 1 (kg=0 lane elem 0), else 0
    f16x8 hb = {};
    if (kg == 0) hb[0] = (_Float16)1.0f;

    // ---- h -> registers as B-frags: h[ks] = h[rowg, 16ks+8kg+0..7] ----
    f16x8 h[16], rh[16], hn[16];
    {
        const float* hs = h_in + rowg*256 + kg*8;
        #pragma unroll
        for (int ks = 0; ks < 16; ++ks) {
            f32x4 x = *(const f32x4*)(hs + ks*16);
            f32x4 y = *(const f32x4*)(hs + ks*16 + 4);
            f16x8 v = {(_Float16)x[0],(_Float16)x[1],(_Float16)x[2],(_Float16)x[3],
                       (_Float16)y[0],(_Float16)y[1],(_Float16)y[2],(_Float16)y[3]};
            h[ks] = v;
        }
    }
    __syncthreads();

    stage(W + 0*PANB, WbL,         w, laneC);   // prologue: panel r0
    stage(W + 1*PANB, WbL + 40960, w, laneC);   // panel r1
    int sC = 0, sS = 2;

    for (int t = 0; t < TSTEPS; ++t) {
        f32x16 o0, o1;
        f16x8 zb[4];

        // ---- r gates (panels 0..3): rh[4c+i] = sigm(h@Wr_c + rb) * h ----
#define RPH(SP_STG, C)                                                        \
        PHASE(SP_STG, {                                                       \
            f32x16 a0 = {}, a1 = {};                                          \
            gemm17(panL, h, hb, a0, a1);                                      \
            rh[4*(C)+0] = pkS(a0, 0)*h[4*(C)+0];                              \
            rh[4*(C)+1] = pkS(a0, 8)*h[4*(C)+1];                              \
            rh[4*(C)+2] = pkS(a1, 0)*h[4*(C)+2];                              \
            rh[4*(C)+3] = pkS(a1, 8)*h[4*(C)+3]; })
        RPH(2, 0); RPH(3, 1); RPH(4, 2); RPH(8, 3);
#undef RPH

        // ---- per chunk c: z -> W1 -> W2+combine ----
#define ZPH(SP_STG, C)                                                        \
        PHASE(SP_STG, {                                                       \
            f32x16 a0 = {}, a1 = {};                                          \
            gemm17(panL, h, hb, a0, a1);                                      \
            zb[0] = pkS(a0, 0); zb[1] = pkS(a0, 8);                           \
            zb[2] = pkS(a1, 0); zb[3] = pkS(a1, 8); })
#define W1PH(SP_STG, C)                                                       \
        PHASE(SP_STG, {                                                       \
            o0 = (f32x16){}; o1 = (f32x16){};                                 \
            gemm17(panL, h, hb, o0, o1); })
#define W2PH(SP_STG, C)                                                       \
        PHASE(SP_STG, {                                                       \
            gemm16(panL, rh, o0, o1);                                         \
            f16x8 u0 = pkT(o0, 0), u1 = pkT(o0, 8);                           \
            f16x8 u2 = pkT(o1, 0), u3 = pkT(o1, 8);                           \
            hn[4*(C)+0] = u0 + zb[0]*(h[4*(C)+0] - u0);                       \
            hn[4*(C)+1] = u1 + zb[1]*(h[4*(C)+1] - u1);                       \
            hn[4*(C)+2] = u2 + zb[2]*(h[4*(C)+2] - u2);                       \
            hn[4*(C)+3] = u3 + zb[3]*(h[4*(C)+3] - u3); })

        ZPH(12, 0); W1PH(5, 0); W2PH(9,  0);
        ZPH(13, 1); W1PH(6, 1); W2PH(10, 1);
        ZPH(14, 2); W1PH(7, 2); W2PH(11, 2);
        ZPH(15, 3); W1PH(16,3); W2PH(0,  3);
#undef ZPH
#undef W1PH
#undef W2PH

        // h <- h_new
        #pragma unroll
        for (int i = 0; i < 16; ++i) h[i] = hn[i];

        // ---- proj (panel 16): out_t = h_new @ Wp^T + pb ----
        PHASE(1, {
            f32x16 a0 = {}, a1 = {};
            gemm17(panL, h, hb, a0, a1);
            float* op = out + (rowg*TSTEPS + t)*64 + 4*kg;
            _Pragma("unroll")
            for (int j = 0; j < 4; ++j) {
                f32x4 v0 = {a0[4*j], a0[4*j+1], a0[4*j+2], a0[4*j+3]};
                f32x4 v1 = {a1[4*j], a1[4*j+1], a1[4*j+2], a1[4*j+3]};
                *(f32x4*)(op + 8*j)      = v0;
                *(f32x4*)(op + 32 + 8*j) = v1;
            }
        });
    }
}

extern "C" void kernel_launch(void* const* d_in, const int* in_sizes, int n_in,
                              void* d_out, int out_size, void* d_ws, size_t ws_size,
                              hipStream_t stream) {
    // inputs: 0:x(=12) 1:h 2:gate_w 3:gate_b 4:out_w 5:out_b 6:proj_w 7:proj_b
    const float* h  = (const float*)d_in[1];
    const float* gw = (const float*)d_in[2];
    const float* gb = (const float*)d_in[3];
    const float* ow = (const float*)d_in[4];
    const float* ob = (const float*)d_in[5];
    const float* pw = (const float*)d_in[6];
    const float* pb = (const float*)d_in[7];
    if (ws_size < (size_t)WS_BYTES) return;
    _Float16* ws = (_Float16*)d_ws;

    hipLaunchKernelGGL(prep_weights, dim3((WS_TOTAL_F16 + 255)/256), dim3(256),
                       0, stream, gw, ow, pw, gb, ob, pb, ws);
    hipLaunchKernelGGL(gru_dec, dim3(65536/256), dim3(512), 0, stream,
                       h, ws, (float*)d_out);
}